// Round 1
// baseline (2005.500 us; speedup 1.0000x reference)
//
#include <hip/hip_runtime.h>

#define HH 32
#define VV 95
#define TT 256
#define NSEQ 8   // sequences per block

__device__ __forceinline__ float fast_sigmoid(float v) {
    return __builtin_amdgcn_rcpf(1.0f + __expf(-v));
}
__device__ __forceinline__ float fast_tanh(float v) {
    // tanh(x) = 1 - 2/(e^{2x}+1); safe at +-inf
    return 1.0f - 2.0f * __builtin_amdgcn_rcpf(__expf(2.0f * v) + 1.0f);
}

// LDS layout (floats):
//  sWih1 : 96*95            = 9120   (rows length 95, odd => conflict-free)
//  sWhh1 : 96*33            = 3168   (pad stride 33 => conflict-free)
//  sWhh2 : 3168
//  sWhh3 : 3168
//  sWih2 : 3168
//  sWih3 : 3168
//  sWfc  : 96*33            = 3168   (row 95 zeroed)
//  sbias : 672  (bih1,bhh1,bih2,bhh2,bih3,bhh3 (96 each), bfc padded to 96)
//  xb    : 8*96             = 768
//  hb    : 3*2*8*32         = 1536   (layer, dbuf, seq, k)
//  total = 31104 floats = 124416 B

extern "C" __global__ void __launch_bounds__(256) gru_fused(
    const float* __restrict__ x,
    const float* __restrict__ Wih1, const float* __restrict__ Whh1,
    const float* __restrict__ bih1, const float* __restrict__ bhh1,
    const float* __restrict__ Wih2, const float* __restrict__ Whh2,
    const float* __restrict__ bih2, const float* __restrict__ bhh2,
    const float* __restrict__ Wih3, const float* __restrict__ Whh3,
    const float* __restrict__ bih3, const float* __restrict__ bhh3,
    const float* __restrict__ Wfc,  const float* __restrict__ bfc,
    float* __restrict__ out)
{
    extern __shared__ float sm[];
    float* sWih1 = sm;                 // 9120
    float* sWhh1 = sWih1 + 9120;       // 3168
    float* sWhh2 = sWhh1 + 3168;
    float* sWhh3 = sWhh2 + 3168;
    float* sWih2 = sWhh3 + 3168;
    float* sWih3 = sWih2 + 3168;
    float* sWfc  = sWih3 + 3168;
    float* sbias = sWfc  + 3168;       // 672
    float* xb    = sbias + 672;        // 768
    float* hb    = xb    + 768;        // 1536

    const int tid = threadIdx.x;

    // ---- stage weights into LDS ----
    for (int i = tid; i < 96 * 95; i += 256) sWih1[i] = Wih1[i];
    for (int i = tid; i < 96 * 32; i += 256) {
        const int g = i >> 5, k = i & 31;
        const int p = g * 33 + k;
        sWhh1[p] = Whh1[i];
        sWhh2[p] = Whh2[i];
        sWhh3[p] = Whh3[i];
        sWih2[p] = Wih2[i];
        sWih3[p] = Wih3[i];
    }
    for (int i = tid; i < 95 * 32; i += 256) {
        const int v = i >> 5, k = i & 31;
        sWfc[v * 33 + k] = Wfc[i];
    }
    if (tid < 33) sWfc[95 * 33 + tid] = 0.0f;   // pad row 95
    if (tid < 96) {
        sbias[tid]        = bih1[tid];
        sbias[96  + tid]  = bhh1[tid];
        sbias[192 + tid]  = bih2[tid];
        sbias[288 + tid]  = bhh2[tid];
        sbias[384 + tid]  = bih3[tid];
        sbias[480 + tid]  = bhh3[tid];
        sbias[576 + tid]  = (tid < 95) ? bfc[tid] : 0.0f;
    }
    for (int i = tid; i < 1536; i += 256) hb[i] = 0.0f;
    __syncthreads();

    // ---- per-thread mapping ----
    const int s = tid >> 5;       // sequence within block
    const int j = tid & 31;       // hidden unit
    const size_t b = (size_t)blockIdx.x * NSEQ + s;
    const float* xrow = x   + b * (size_t)(TT * VV);
    float*       orow = out + b * (size_t)(TT * VV);
    float* xbs = xb + s * 96;

    // bias registers
    const float bi1r = sbias[j],        bi1z = sbias[32 + j],  bi1n = sbias[64 + j];
    const float bh1r = sbias[96 + j],   bh1z = sbias[128 + j], bh1n = sbias[160 + j];
    const float bi2r = sbias[192 + j],  bi2z = sbias[224 + j], bi2n = sbias[256 + j];
    const float bh2r = sbias[288 + j],  bh2z = sbias[320 + j], bh2n = sbias[352 + j];
    const float bi3r = sbias[384 + j],  bi3z = sbias[416 + j], bi3n = sbias[448 + j];
    const float bh3r = sbias[480 + j],  bh3z = sbias[512 + j], bh3n = sbias[544 + j];
    const float bf0  = sbias[576 + j],  bf1  = sbias[608 + j], bf2  = sbias[640 + j];

    // weight row pointers
    const float* w1r = sWih1 + j * 95;
    const float* w1z = sWih1 + (32 + j) * 95;
    const float* w1n = sWih1 + (64 + j) * 95;
    const float* u1r = sWhh1 + j * 33;
    const float* u1z = sWhh1 + (32 + j) * 33;
    const float* u1n = sWhh1 + (64 + j) * 33;
    const float* v2r = sWih2 + j * 33;
    const float* v2z = sWih2 + (32 + j) * 33;
    const float* v2n = sWih2 + (64 + j) * 33;
    const float* u2r = sWhh2 + j * 33;
    const float* u2z = sWhh2 + (32 + j) * 33;
    const float* u2n = sWhh2 + (64 + j) * 33;
    const float* v3r = sWih3 + j * 33;
    const float* v3z = sWih3 + (32 + j) * 33;
    const float* v3n = sWih3 + (64 + j) * 33;
    const float* u3r = sWhh3 + j * 33;
    const float* u3z = sWhh3 + (32 + j) * 33;
    const float* u3n = sWhh3 + (64 + j) * 33;
    const float* wf0 = sWfc + j * 33;
    const float* wf1 = sWfc + (32 + j) * 33;
    const float* wf2 = sWfc + (64 + j) * 33;

    float* hb0 = hb;            // layer1: [2][8][32]
    float* hb1 = hb + 512;      // layer2
    float* hb2 = hb + 1024;     // layer3

    for (int t = 0; t < TT; ++t) {
        const int cur = t & 1, prv = cur ^ 1;

        // stage this timestep's x row for our sequence
        const float* xg = xrow + t * VV;
        for (int i = j; i < VV; i += 32) xbs[i] = xg[i];
        __syncthreads();

        // ---------- layer 1 ----------
        float ar = bi1r, az = bi1z, an = bi1n;
        for (int i = 0; i < VV; ++i) {
            const float xi = xbs[i];
            ar = fmaf(w1r[i], xi, ar);
            az = fmaf(w1z[i], xi, az);
            an = fmaf(w1n[i], xi, an);
        }
        const float* h1p = hb0 + prv * 256 + s * 32;
        float hr = bh1r, hz = bh1z, hn = bh1n;
        #pragma unroll
        for (int k = 0; k < HH; ++k) {
            const float hk = h1p[k];
            hr = fmaf(u1r[k], hk, hr);
            hz = fmaf(u1z[k], hk, hz);
            hn = fmaf(u1n[k], hk, hn);
        }
        {
            const float r = fast_sigmoid(ar + hr);
            const float z = fast_sigmoid(az + hz);
            const float n = fast_tanh(an + r * hn);
            const float h1 = (1.0f - z) * n + z * h1p[j];
            hb0[cur * 256 + s * 32 + j] = h1;
        }
        __syncthreads();

        // ---------- layer 2 ----------
        const float* h1c = hb0 + cur * 256 + s * 32;
        float a2r = bi2r, a2z = bi2z, a2n = bi2n;
        #pragma unroll
        for (int k = 0; k < HH; ++k) {
            const float hk = h1c[k];
            a2r = fmaf(v2r[k], hk, a2r);
            a2z = fmaf(v2z[k], hk, a2z);
            a2n = fmaf(v2n[k], hk, a2n);
        }
        const float* h2p = hb1 + prv * 256 + s * 32;
        float h2r = bh2r, h2z = bh2z, h2n = bh2n;
        #pragma unroll
        for (int k = 0; k < HH; ++k) {
            const float hk = h2p[k];
            h2r = fmaf(u2r[k], hk, h2r);
            h2z = fmaf(u2z[k], hk, h2z);
            h2n = fmaf(u2n[k], hk, h2n);
        }
        {
            const float r = fast_sigmoid(a2r + h2r);
            const float z = fast_sigmoid(a2z + h2z);
            const float n = fast_tanh(a2n + r * h2n);
            const float h2 = (1.0f - z) * n + z * h2p[j];
            hb1[cur * 256 + s * 32 + j] = h2;
        }
        __syncthreads();

        // ---------- layer 3 ----------
        const float* h2c = hb1 + cur * 256 + s * 32;
        float a3r = bi3r, a3z = bi3z, a3n = bi3n;
        #pragma unroll
        for (int k = 0; k < HH; ++k) {
            const float hk = h2c[k];
            a3r = fmaf(v3r[k], hk, a3r);
            a3z = fmaf(v3z[k], hk, a3z);
            a3n = fmaf(v3n[k], hk, a3n);
        }
        const float* h3p = hb2 + prv * 256 + s * 32;
        float h3r = bh3r, h3z = bh3z, h3n = bh3n;
        #pragma unroll
        for (int k = 0; k < HH; ++k) {
            const float hk = h3p[k];
            h3r = fmaf(u3r[k], hk, h3r);
            h3z = fmaf(u3z[k], hk, h3z);
            h3n = fmaf(u3n[k], hk, h3n);
        }
        {
            const float r = fast_sigmoid(a3r + h3r);
            const float z = fast_sigmoid(a3z + h3z);
            const float n = fast_tanh(a3n + r * h3n);
            const float h3 = (1.0f - z) * n + z * h3p[j];
            hb2[cur * 256 + s * 32 + j] = h3;
        }
        __syncthreads();

        // ---------- FC head ----------
        const float* h3c = hb2 + cur * 256 + s * 32;
        float o0 = bf0, o1 = bf1, o2 = bf2;
        #pragma unroll
        for (int k = 0; k < HH; ++k) {
            const float hk = h3c[k];
            o0 = fmaf(wf0[k], hk, o0);
            o1 = fmaf(wf1[k], hk, o1);
            o2 = fmaf(wf2[k], hk, o2);
        }
        float* op = orow + t * VV;
        op[j]      = o0;
        op[32 + j] = o1;
        if (j < 31) op[64 + j] = o2;
    }
}

extern "C" void kernel_launch(void* const* d_in, const int* in_sizes, int n_in,
                              void* d_out, int out_size, void* d_ws, size_t ws_size,
                              hipStream_t stream) {
    const float* x    = (const float*)d_in[0];
    const float* Wih1 = (const float*)d_in[1];
    const float* Whh1 = (const float*)d_in[2];
    const float* bih1 = (const float*)d_in[3];
    const float* bhh1 = (const float*)d_in[4];
    const float* Wih2 = (const float*)d_in[5];
    const float* Whh2 = (const float*)d_in[6];
    const float* bih2 = (const float*)d_in[7];
    const float* bhh2 = (const float*)d_in[8];
    const float* Wih3 = (const float*)d_in[9];
    const float* Whh3 = (const float*)d_in[10];
    const float* bih3 = (const float*)d_in[11];
    const float* bhh3 = (const float*)d_in[12];
    const float* Wfc  = (const float*)d_in[13];
    const float* bfc  = (const float*)d_in[14];
    float* out = (float*)d_out;

    const int lds_bytes = 31104 * 4;   // 124416 B
    hipFuncSetAttribute((const void*)gru_fused,
                        hipFuncAttributeMaxDynamicSharedMemorySize, lds_bytes);

    dim3 grid(256), block(256);
    hipLaunchKernelGGL(gru_fused, grid, block, lds_bytes, stream,
                       x, Wih1, Whh1, bih1, bhh1,
                       Wih2, Whh2, bih2, bhh2,
                       Wih3, Whh3, bih3, bhh3,
                       Wfc, bfc, out);
}

// Round 2
// 1053.631 us; speedup vs baseline: 1.9034x; 1.9034x over previous
//
#include <hip/hip_runtime.h>

#define HH 32
#define VV 95
#define TT 256

__device__ __forceinline__ float fast_sigmoid(float v) {
    return __builtin_amdgcn_rcpf(1.0f + __expf(-v));
}
__device__ __forceinline__ float fast_tanh(float v) {
    return 1.0f - 2.0f * __builtin_amdgcn_rcpf(__expf(2.0f * v) + 1.0f);
}
__device__ __forceinline__ void wave_fence() {
    // compiler memory fence + scheduling fence; DS pipe is in-order per wave,
    // drain lgkmcnt so all lanes' LDS writes are visible before next reads.
    asm volatile("s_waitcnt lgkmcnt(0)" ::: "memory");
    __builtin_amdgcn_wave_barrier();
}

// ---------------- Layer 1: x-proj from LDS weights, Whh1 in registers ----------
// Writes h1 -> out[b, t, 0:32]
extern "C" __global__ void __launch_bounds__(256, 1) gru_l1(
    const float* __restrict__ x,
    const float* __restrict__ Wih1, const float* __restrict__ Whh1,
    const float* __restrict__ bih1, const float* __restrict__ bhh1,
    float* __restrict__ out)
{
    __shared__ float sW[96 * 95];      // stride 95 (odd) => conflict-free
    __shared__ float xst[2][8][96];    // double-buffered x row per seq
    __shared__ float hb[8][32];        // h state per seq (intra-wave only)

    const int tid = threadIdx.x;
    for (int i = tid; i < 96 * 95; i += 256) sW[i] = Wih1[i];

    const int s = tid >> 5, j = tid & 31;   // seq-in-block, hidden unit
    float ur[32], uz[32], un[32];
    #pragma unroll
    for (int k = 0; k < 32; ++k) {
        ur[k] = Whh1[j * 32 + k];
        uz[k] = Whh1[(32 + j) * 32 + k];
        un[k] = Whh1[(64 + j) * 32 + k];
    }
    const float bir = bih1[j], biz = bih1[32 + j], bin_ = bih1[64 + j];
    const float bhr = bhh1[j], bhz = bhh1[32 + j], bhn = bhh1[64 + j];

    const size_t b = (size_t)blockIdx.x * 8 + s;
    const float* xrow = x + b * (size_t)(TT * VV);
    float* orow = out + b * (size_t)(TT * VV);

    hb[s][j] = 0.0f;
    float hj = 0.0f;
    for (int i = j; i < VV; i += 32) xst[0][s][i] = xrow[i];
    __syncthreads();   // one-time: sW staged by whole block

    const float* wr = sW + j * 95;
    const float* wz = sW + (32 + j) * 95;
    const float* wn = sW + (64 + j) * 95;

    for (int t = 0; t < TT; ++t) {
        const int cur = t & 1;
        // prefetch next x row (3 floats/lane)
        float p0 = 0.f, p1 = 0.f, p2 = 0.f;
        if (t + 1 < TT) {
            const float* xn_ = xrow + (t + 1) * VV;
            p0 = xn_[j]; p1 = xn_[32 + j];
            p2 = (j < 31) ? xn_[64 + j] : 0.f;
        }
        const float* xs = xst[cur][s];
        float ar = bir, az = biz, an = bin_;
        #pragma unroll
        for (int i4 = 0; i4 < 23; ++i4) {           // 92 elements as float4
            const float4 xv = ((const float4*)xs)[i4];
            const int i = i4 * 4;
            ar = fmaf(wr[i    ], xv.x, ar); az = fmaf(wz[i    ], xv.x, az); an = fmaf(wn[i    ], xv.x, an);
            ar = fmaf(wr[i + 1], xv.y, ar); az = fmaf(wz[i + 1], xv.y, az); an = fmaf(wn[i + 1], xv.y, an);
            ar = fmaf(wr[i + 2], xv.z, ar); az = fmaf(wz[i + 2], xv.z, az); an = fmaf(wn[i + 2], xv.z, an);
            ar = fmaf(wr[i + 3], xv.w, ar); az = fmaf(wz[i + 3], xv.w, az); an = fmaf(wn[i + 3], xv.w, an);
        }
        #pragma unroll
        for (int i = 92; i < 95; ++i) {
            const float xi = xs[i];
            ar = fmaf(wr[i], xi, ar); az = fmaf(wz[i], xi, az); an = fmaf(wn[i], xi, an);
        }
        float hr = bhr, hz = bhz, hn = bhn;
        #pragma unroll
        for (int k = 0; k < 32; ++k) {
            const float hk = hb[s][k];
            hr = fmaf(ur[k], hk, hr); hz = fmaf(uz[k], hk, hz); hn = fmaf(un[k], hk, hn);
        }
        const float r = fast_sigmoid(ar + hr);
        const float z = fast_sigmoid(az + hz);
        const float n = fast_tanh(an + r * hn);
        hj = (1.0f - z) * n + z * hj;

        asm volatile("" ::: "memory");   // reads above stay above
        hb[s][j] = hj;
        orow[t * 95 + j] = hj;           // h1 -> cols 0:32
        if (t + 1 < TT) {
            float* xd = xst[cur ^ 1][s];
            xd[j] = p0; xd[32 + j] = p1;
            if (j < 31) xd[64 + j] = p2;
        }
        wave_fence();
    }
}

// ---------------- Layer 2: all weights in registers -------------------------
// Reads h1 from out[...,0:32], writes h2 -> out[...,32:64]
extern "C" __global__ void __launch_bounds__(256, 1) gru_l2(
    const float* __restrict__ Wih2, const float* __restrict__ Whh2,
    const float* __restrict__ bih2, const float* __restrict__ bhh2,
    float* __restrict__ out)
{
    __shared__ float ist[2][8][32];
    __shared__ float hb[8][32];
    const int tid = threadIdx.x;
    const int s = tid >> 5, j = tid & 31;

    float vr[32], vz[32], vn[32], ur[32], uz[32], un[32];
    #pragma unroll
    for (int k = 0; k < 32; ++k) {
        vr[k] = Wih2[j * 32 + k];        vz[k] = Wih2[(32 + j) * 32 + k];  vn[k] = Wih2[(64 + j) * 32 + k];
        ur[k] = Whh2[j * 32 + k];        uz[k] = Whh2[(32 + j) * 32 + k];  un[k] = Whh2[(64 + j) * 32 + k];
    }
    const float bir = bih2[j], biz = bih2[32 + j], bin_ = bih2[64 + j];
    const float bhr = bhh2[j], bhz = bhh2[32 + j], bhn = bhh2[64 + j];

    const size_t b = (size_t)blockIdx.x * 8 + s;
    float* orow = out + b * (size_t)(TT * VV);

    hb[s][j] = 0.0f;
    float hj = 0.0f;
    ist[0][s][j] = orow[j];              // h1[b,0]
    wave_fence();

    for (int t = 0; t < TT; ++t) {
        const int cur = t & 1;
        float pn = 0.f;
        if (t + 1 < TT) pn = orow[(t + 1) * 95 + j];   // next h1

        const float* in = ist[cur][s];
        float ar = bir, az = biz, an = bin_;
        float hr = bhr, hz = bhz, hn = bhn;
        #pragma unroll
        for (int k = 0; k < 32; ++k) {
            const float ik = in[k], hk = hb[s][k];
            ar = fmaf(vr[k], ik, ar); az = fmaf(vz[k], ik, az); an = fmaf(vn[k], ik, an);
            hr = fmaf(ur[k], hk, hr); hz = fmaf(uz[k], hk, hz); hn = fmaf(un[k], hk, hn);
        }
        const float r = fast_sigmoid(ar + hr);
        const float z = fast_sigmoid(az + hz);
        const float n = fast_tanh(an + r * hn);
        hj = (1.0f - z) * n + z * hj;

        orow[t * 95 + 32 + j] = hj;      // h2 -> cols 32:64
        asm volatile("" ::: "memory");
        hb[s][j] = hj;
        if (t + 1 < TT) ist[cur ^ 1][s][j] = pn;
        wave_fence();
    }
}

// ---------------- Layer 3 + FC head: weights in registers -------------------
// Reads h2 from out[...,32:64], writes final out[...,0:95]
extern "C" __global__ void __launch_bounds__(256, 1) gru_l3fc(
    const float* __restrict__ Wih3, const float* __restrict__ Whh3,
    const float* __restrict__ bih3, const float* __restrict__ bhh3,
    const float* __restrict__ Wfc,  const float* __restrict__ bfc,
    float* __restrict__ out)
{
    __shared__ float ist[2][8][32];
    __shared__ float hb[8][32];
    const int tid = threadIdx.x;
    const int s = tid >> 5, j = tid & 31;

    float vr[32], vz[32], vn[32], ur[32], uz[32], un[32];
    float wf0[32], wf1[32], wf2[32];
    #pragma unroll
    for (int k = 0; k < 32; ++k) {
        vr[k] = Wih3[j * 32 + k];        vz[k] = Wih3[(32 + j) * 32 + k];  vn[k] = Wih3[(64 + j) * 32 + k];
        ur[k] = Whh3[j * 32 + k];        uz[k] = Whh3[(32 + j) * 32 + k];  un[k] = Whh3[(64 + j) * 32 + k];
        wf0[k] = Wfc[j * 32 + k];
        wf1[k] = Wfc[(32 + j) * 32 + k];
        wf2[k] = (j < 31) ? Wfc[(64 + j) * 32 + k] : 0.f;
    }
    const float bir = bih3[j], biz = bih3[32 + j], bin_ = bih3[64 + j];
    const float bhr = bhh3[j], bhz = bhh3[32 + j], bhn = bhh3[64 + j];
    const float bf0 = bfc[j], bf1 = bfc[32 + j], bf2 = (j < 31) ? bfc[64 + j] : 0.f;

    const size_t b = (size_t)blockIdx.x * 8 + s;
    float* orow = out + b * (size_t)(TT * VV);

    hb[s][j] = 0.0f;
    float hj = 0.0f;
    ist[0][s][j] = orow[32 + j];         // h2[b,0]
    wave_fence();

    for (int t = 0; t < TT; ++t) {
        const int cur = t & 1;
        float pn = 0.f;
        if (t + 1 < TT) pn = orow[(t + 1) * 95 + 32 + j];  // next h2 (read before row overwrite)

        const float* in = ist[cur][s];
        float ar = bir, az = biz, an = bin_;
        float hr = bhr, hz = bhz, hn = bhn;
        #pragma unroll
        for (int k = 0; k < 32; ++k) {
            const float ik = in[k], hk = hb[s][k];
            ar = fmaf(vr[k], ik, ar); az = fmaf(vz[k], ik, az); an = fmaf(vn[k], ik, an);
            hr = fmaf(ur[k], hk, hr); hz = fmaf(uz[k], hk, hz); hn = fmaf(un[k], hk, hn);
        }
        const float r = fast_sigmoid(ar + hr);
        const float z = fast_sigmoid(az + hz);
        const float n = fast_tanh(an + r * hn);
        hj = (1.0f - z) * n + z * hj;

        asm volatile("" ::: "memory");
        hb[s][j] = hj;                   // publish h3 for FC broadcasts
        wave_fence();

        float o0 = bf0, o1 = bf1, o2 = bf2;
        #pragma unroll
        for (int k = 0; k < 32; ++k) {
            const float hk = hb[s][k];
            o0 = fmaf(wf0[k], hk, o0); o1 = fmaf(wf1[k], hk, o1); o2 = fmaf(wf2[k], hk, o2);
        }
        float* op = orow + t * 95;
        op[j] = o0; op[32 + j] = o1;
        if (j < 31) op[64 + j] = o2;

        asm volatile("" ::: "memory");
        if (t + 1 < TT) ist[cur ^ 1][s][j] = pn;
        wave_fence();
    }
}

extern "C" void kernel_launch(void* const* d_in, const int* in_sizes, int n_in,
                              void* d_out, int out_size, void* d_ws, size_t ws_size,
                              hipStream_t stream) {
    const float* x    = (const float*)d_in[0];
    const float* Wih1 = (const float*)d_in[1];
    const float* Whh1 = (const float*)d_in[2];
    const float* bih1 = (const float*)d_in[3];
    const float* bhh1 = (const float*)d_in[4];
    const float* Wih2 = (const float*)d_in[5];
    const float* Whh2 = (const float*)d_in[6];
    const float* bih2 = (const float*)d_in[7];
    const float* bhh2 = (const float*)d_in[8];
    const float* Wih3 = (const float*)d_in[9];
    const float* Whh3 = (const float*)d_in[10];
    const float* bih3 = (const float*)d_in[11];
    const float* bhh3 = (const float*)d_in[12];
    const float* Wfc  = (const float*)d_in[13];
    const float* bfc  = (const float*)d_in[14];
    float* out = (float*)d_out;

    dim3 grid(256), block(256);
    hipLaunchKernelGGL(gru_l1, grid, block, 0, stream, x, Wih1, Whh1, bih1, bhh1, out);
    hipLaunchKernelGGL(gru_l2, grid, block, 0, stream, Wih2, Whh2, bih2, bhh2, out);
    hipLaunchKernelGGL(gru_l3fc, grid, block, 0, stream, Wih3, Whh3, bih3, bhh3, Wfc, bfc, out);
}

// Round 3
// 929.535 us; speedup vs baseline: 2.1575x; 1.1335x over previous
//
#include <hip/hip_runtime.h>

#define TT 256
#define VV 95

__device__ __forceinline__ float fast_sigmoid(float v) {
    return __builtin_amdgcn_rcpf(1.0f + __expf(-v));
}
__device__ __forceinline__ float fast_tanh(float v) {
    return 1.0f - 2.0f * __builtin_amdgcn_rcpf(__expf(2.0f * v) + 1.0f);
}
__device__ __forceinline__ void wave_fence() {
    asm volatile("s_waitcnt lgkmcnt(0)" ::: "memory");
    __builtin_amdgcn_wave_barrier();
}

__device__ __forceinline__ float dot16(const float* w, float4 a, float4 b, float4 c, float4 d) {
    float s = 0.0f;
    s = fmaf(w[0],  a.x, s); s = fmaf(w[1],  a.y, s); s = fmaf(w[2],  a.z, s); s = fmaf(w[3],  a.w, s);
    s = fmaf(w[4],  b.x, s); s = fmaf(w[5],  b.y, s); s = fmaf(w[6],  b.z, s); s = fmaf(w[7],  b.w, s);
    s = fmaf(w[8],  c.x, s); s = fmaf(w[9],  c.y, s); s = fmaf(w[10], c.z, s); s = fmaf(w[11], c.w, s);
    s = fmaf(w[12], d.x, s); s = fmaf(w[13], d.y, s); s = fmaf(w[14], d.z, s); s = fmaf(w[15], d.w, s);
    return s;
}

// ================= K0: xp[row,g] = x[row,:]@W1[g,:] + bih1[g] -> out[row*95+g], g<95
__global__ void __launch_bounds__(256) k0_xproj(
    const float* __restrict__ x, const float* __restrict__ Wih1,
    const float* __restrict__ bih1, float* __restrict__ out)
{
    __shared__ float xs[64 * 98];   // 64 rows, stride 98 (pad zeroed at [95])
    __shared__ float ws[96 * 98];   // 96 gate rows, stride 98
    const int tid = threadIdx.x;
    const size_t row0 = (size_t)blockIdx.x * 64;

    const float* xg = x + row0 * VV;
    for (int i = tid; i < 64 * VV; i += 256) {
        const int r = i / VV, k = i - r * VV;
        xs[r * 98 + k] = xg[i];
    }
    for (int i = tid; i < 96 * VV; i += 256) {
        const int g = i / VV, k = i - g * VV;
        ws[g * 98 + k] = Wih1[i];
    }
    if (tid < 64) xs[tid * 98 + VV] = 0.0f;
    if (tid < 96) ws[tid * 98 + VV] = 0.0f;

    const int rq = tid >> 3;   // 32 groups x 2 rows
    const int gq = tid & 7;    // 8 groups x 12 outputs
    float acc[2][12];
    #pragma unroll
    for (int c = 0; c < 12; ++c) {
        const float bv = bih1[gq * 12 + c];
        acc[0][c] = bv; acc[1][c] = bv;
    }
    __syncthreads();

    const float* xr0 = xs + (rq * 2) * 98;
    const float* xr1 = xr0 + 98;
    const float* wb_ = ws + (gq * 12) * 98;
    #pragma unroll 2
    for (int k2 = 0; k2 < 48; ++k2) {
        const int k = k2 * 2;
        const float2 xv0 = *(const float2*)(xr0 + k);
        const float2 xv1 = *(const float2*)(xr1 + k);
        #pragma unroll
        for (int c = 0; c < 12; ++c) {
            const float2 wv = *(const float2*)(wb_ + c * 98 + k);
            acc[0][c] = fmaf(wv.x, xv0.x, acc[0][c]);
            acc[0][c] = fmaf(wv.y, xv0.y, acc[0][c]);
            acc[1][c] = fmaf(wv.x, xv1.x, acc[1][c]);
            acc[1][c] = fmaf(wv.y, xv1.y, acc[1][c]);
        }
    }
    #pragma unroll
    for (int rr = 0; rr < 2; ++rr) {
        float* orow = out + (row0 + rq * 2 + rr) * VV;
        #pragma unroll
        for (int c = 0; c < 12; ++c) {
            const int g = gq * 12 + c;
            if (g < VV) orow[g] = acc[rr][c];
        }
    }
}

// ================= L1 recurrent: reads xp from out, h-dots from reg weights
__device__ __forceinline__ void l1_step(
    int t, int j, int p, int wid, int i0, int i1,
    const float* __restrict__ xrow, float* __restrict__ orow, float (*hb)[32],
    const float* ur, const float* uz, const float* un,
    float wa, float wb, float bn95, float bhr, float bhz, float bhn,
    float& hj, float& xr, float& xz, float& xn, float& xa, float& xb)
{
    float nr = 0.f, nz = 0.f, nn = 0.f, na = 0.f, nb = 0.f;
    if (t + 2 < TT) {
        const float* nx = orow + (t + 2) * VV;
        nr = nx[j]; nz = nx[32 + j];
        if (j < 31) nn = nx[64 + j];
        const float* xx = xrow + (t + 2) * VV;
        if (i0 < VV) na = xx[i0];
        if (i1 < VV) nb = xx[i1];
    }
    const float4* hv = (const float4*)(&hb[wid][16 * p]);
    const float4 h0 = hv[0], h1 = hv[1], h2 = hv[2], h3 = hv[3];
    float hr = dot16(ur, h0, h1, h2, h3);
    float hz = dot16(uz, h0, h1, h2, h3);
    float hn = dot16(un, h0, h1, h2, h3);
    // recompute xn[31]: 64-lane distributed dot + butterfly (overlaps h-dots)
    float v = fmaf(wa, xa, wb * xb);
    v += __shfl_xor(v, 1);  v += __shfl_xor(v, 2);  v += __shfl_xor(v, 4);
    v += __shfl_xor(v, 8);  v += __shfl_xor(v, 16); v += __shfl_xor(v, 32);
    const float xnf = (j == 31) ? (v + bn95) : xn;
    hr += __shfl_xor(hr, 32);
    hz += __shfl_xor(hz, 32);
    hn += __shfl_xor(hn, 32);
    const float r = fast_sigmoid(xr + hr + bhr);
    const float z = fast_sigmoid(xz + hz + bhz);
    const float n = fast_tanh(xnf + r * (hn + bhn));
    hj = (1.0f - z) * n + z * hj;
    asm volatile("" ::: "memory");
    if (p == 0) { hb[wid][j] = hj; orow[t * VV + j] = hj; }
    xr = nr; xz = nz; xn = nn; xa = na; xb = nb;
    wave_fence();
}

extern "C" __global__ void __launch_bounds__(256) gru_l1r(
    const float* __restrict__ x, const float* __restrict__ Wih1,
    const float* __restrict__ Whh1, const float* __restrict__ bih1,
    const float* __restrict__ bhh1, float* __restrict__ out)
{
    __shared__ __align__(16) float hb[4][32];
    const int tid = threadIdx.x;
    const int wid = tid >> 6, l = tid & 63, j = l & 31, p = l >> 5;

    float ur[16], uz[16], un[16];
    #pragma unroll
    for (int c = 0; c < 16; ++c) {
        ur[c] = Whh1[j * 32 + 16 * p + c];
        uz[c] = Whh1[(32 + j) * 32 + 16 * p + c];
        un[c] = Whh1[(64 + j) * 32 + 16 * p + c];
    }
    const float bhr = bhh1[j], bhz = bhh1[32 + j], bhn = bhh1[64 + j];
    const int i0 = 2 * l, i1 = 2 * l + 1;
    const float wa = (i0 < VV) ? Wih1[95 * VV + i0] : 0.0f;
    const float wb = (i1 < VV) ? Wih1[95 * VV + i1] : 0.0f;
    const float bn95 = bih1[95];

    const size_t b = (size_t)blockIdx.x * 4 + wid;
    const float* xrow = x + b * (size_t)(TT * VV);
    float* orow = out + b * (size_t)(TT * VV);

    if (p == 0) hb[wid][j] = 0.0f;
    float hj = 0.0f;
    // preload banks A(t=0), B(t=1)
    float AxR = orow[j], AxZ = orow[32 + j];
    float AxN = (j < 31) ? orow[64 + j] : 0.f;
    float AxA = (i0 < VV) ? xrow[i0] : 0.f;
    float AxB = (i1 < VV) ? xrow[i1] : 0.f;
    const float* r1 = orow + VV; const float* x1 = xrow + VV;
    float BxR = r1[j], BxZ = r1[32 + j];
    float BxN = (j < 31) ? r1[64 + j] : 0.f;
    float BxA = (i0 < VV) ? x1[i0] : 0.f;
    float BxB = (i1 < VV) ? x1[i1] : 0.f;
    wave_fence();

    for (int t = 0; t < TT; t += 2) {
        l1_step(t,     j, p, wid, i0, i1, xrow, orow, hb, ur, uz, un,
                wa, wb, bn95, bhr, bhz, bhn, hj, AxR, AxZ, AxN, AxA, AxB);
        l1_step(t + 1, j, p, wid, i0, i1, xrow, orow, hb, ur, uz, un,
                wa, wb, bn95, bhr, bhz, bhn, hj, BxR, BxZ, BxN, BxA, BxB);
    }
}

// ================= L2 recurrent: in from out cols 0:32, h2 -> cols 32:64
__device__ __forceinline__ void l2_step(
    int t, int j, int p, int wid,
    float* __restrict__ orow, float (*hb)[32], float (*ist)[4][32],
    const float* vr, const float* vz, const float* vn,
    const float* ur, const float* uz, const float* un,
    float br, float bz, float bni, float bnh,
    float& hj, float& pn)
{
    float pnN = (t + 3 < TT) ? orow[(t + 3) * VV + j] : 0.f;
    const int cur = t & 1;
    const float4* iv = (const float4*)(&ist[cur][wid][16 * p]);
    const float4 a0 = iv[0], a1 = iv[1], a2 = iv[2], a3 = iv[3];
    const float4* hv = (const float4*)(&hb[wid][16 * p]);
    const float4 h0 = hv[0], h1 = hv[1], h2 = hv[2], h3 = hv[3];
    float ar = dot16(vr, a0, a1, a2, a3);
    float az = dot16(vz, a0, a1, a2, a3);
    float an = dot16(vn, a0, a1, a2, a3);
    float hr = dot16(ur, h0, h1, h2, h3);
    float hz = dot16(uz, h0, h1, h2, h3);
    float hn = dot16(un, h0, h1, h2, h3);
    float s1 = ar + hr; s1 += __shfl_xor(s1, 32);
    float s2 = az + hz; s2 += __shfl_xor(s2, 32);
    an += __shfl_xor(an, 32);
    hn += __shfl_xor(hn, 32);
    const float r = fast_sigmoid(s1 + br);
    const float z = fast_sigmoid(s2 + bz);
    const float n = fast_tanh(an + bni + r * (hn + bnh));
    hj = (1.0f - z) * n + z * hj;
    asm volatile("" ::: "memory");
    if (p == 0) {
        hb[wid][j] = hj;
        orow[t * VV + 32 + j] = hj;
        ist[cur ^ 1][wid][j] = pn;
    }
    pn = pnN;
    wave_fence();
}

extern "C" __global__ void __launch_bounds__(256) gru_l2r(
    const float* __restrict__ Wih2, const float* __restrict__ Whh2,
    const float* __restrict__ bih2, const float* __restrict__ bhh2,
    float* __restrict__ out)
{
    __shared__ __align__(16) float hb[4][32];
    __shared__ __align__(16) float ist[2][4][32];
    const int tid = threadIdx.x;
    const int wid = tid >> 6, l = tid & 63, j = l & 31, p = l >> 5;

    float vr[16], vz[16], vn[16], ur[16], uz[16], un[16];
    #pragma unroll
    for (int c = 0; c < 16; ++c) {
        vr[c] = Wih2[j * 32 + 16 * p + c];
        vz[c] = Wih2[(32 + j) * 32 + 16 * p + c];
        vn[c] = Wih2[(64 + j) * 32 + 16 * p + c];
        ur[c] = Whh2[j * 32 + 16 * p + c];
        uz[c] = Whh2[(32 + j) * 32 + 16 * p + c];
        un[c] = Whh2[(64 + j) * 32 + 16 * p + c];
    }
    const float br = bih2[j] + bhh2[j];
    const float bz = bih2[32 + j] + bhh2[32 + j];
    const float bni = bih2[64 + j], bnh = bhh2[64 + j];

    const size_t b = (size_t)blockIdx.x * 4 + wid;
    float* orow = out + b * (size_t)(TT * VV);

    if (p == 0) { hb[wid][j] = 0.0f; ist[0][wid][j] = orow[j]; }
    float hj = 0.0f;
    float pnA = orow[1 * VV + j];
    float pnB = orow[2 * VV + j];
    wave_fence();

    for (int t = 0; t < TT; t += 2) {
        l2_step(t,     j, p, wid, orow, hb, ist, vr, vz, vn, ur, uz, un,
                br, bz, bni, bnh, hj, pnA);
        l2_step(t + 1, j, p, wid, orow, hb, ist, vr, vz, vn, ur, uz, un,
                br, bz, bni, bnh, hj, pnB);
    }
}

// ================= L3 + FC: in from cols 32:64, final out all 95 cols
__device__ __forceinline__ void l3_step(
    int t, int j, int p, int wid,
    float* __restrict__ orow, float (*hb)[32], float (*ist)[4][32],
    const float* vr, const float* vz, const float* vn,
    const float* ur, const float* uz, const float* un,
    const float* wf0, const float* wf1, const float* wf2,
    float br, float bz, float bni, float bnh,
    float bf0, float bf1, float bf2,
    float& hj, float& pn)
{
    float pnN = (t + 3 < TT) ? orow[(t + 3) * VV + 32 + j] : 0.f;
    const int cur = t & 1;
    const float4* iv = (const float4*)(&ist[cur][wid][16 * p]);
    const float4 a0 = iv[0], a1 = iv[1], a2 = iv[2], a3 = iv[3];
    const float4* hv = (const float4*)(&hb[wid][16 * p]);
    const float4 h0 = hv[0], h1 = hv[1], h2 = hv[2], h3 = hv[3];
    float ar = dot16(vr, a0, a1, a2, a3);
    float az = dot16(vz, a0, a1, a2, a3);
    float an = dot16(vn, a0, a1, a2, a3);
    float hr = dot16(ur, h0, h1, h2, h3);
    float hz = dot16(uz, h0, h1, h2, h3);
    float hn = dot16(un, h0, h1, h2, h3);
    float s1 = ar + hr; s1 += __shfl_xor(s1, 32);
    float s2 = az + hz; s2 += __shfl_xor(s2, 32);
    an += __shfl_xor(an, 32);
    hn += __shfl_xor(hn, 32);
    const float r = fast_sigmoid(s1 + br);
    const float z = fast_sigmoid(s2 + bz);
    const float n = fast_tanh(an + bni + r * (hn + bnh));
    hj = (1.0f - z) * n + z * hj;
    asm volatile("" ::: "memory");
    if (p == 0) hb[wid][j] = hj;
    wave_fence();
    // FC head on h3(t)
    const float4* gv = (const float4*)(&hb[wid][16 * p]);
    const float4 g0 = gv[0], g1 = gv[1], g2 = gv[2], g3 = gv[3];
    float o0 = dot16(wf0, g0, g1, g2, g3);
    float o1 = dot16(wf1, g0, g1, g2, g3);
    float o2 = dot16(wf2, g0, g1, g2, g3);
    o0 += __shfl_xor(o0, 32);
    o1 += __shfl_xor(o1, 32);
    o2 += __shfl_xor(o2, 32);
    asm volatile("" ::: "memory");
    if (p == 0) {
        float* op = orow + t * VV;
        op[j] = o0 + bf0;
        op[32 + j] = o1 + bf1;
        if (j < 31) op[64 + j] = o2 + bf2;
        ist[cur ^ 1][wid][j] = pn;
    }
    pn = pnN;
    wave_fence();
}

extern "C" __global__ void __launch_bounds__(256) gru_l3fc(
    const float* __restrict__ Wih3, const float* __restrict__ Whh3,
    const float* __restrict__ bih3, const float* __restrict__ bhh3,
    const float* __restrict__ Wfc,  const float* __restrict__ bfc,
    float* __restrict__ out)
{
    __shared__ __align__(16) float hb[4][32];
    __shared__ __align__(16) float ist[2][4][32];
    const int tid = threadIdx.x;
    const int wid = tid >> 6, l = tid & 63, j = l & 31, p = l >> 5;

    float vr[16], vz[16], vn[16], ur[16], uz[16], un[16];
    float wf0[16], wf1[16], wf2[16];
    #pragma unroll
    for (int c = 0; c < 16; ++c) {
        vr[c] = Wih3[j * 32 + 16 * p + c];
        vz[c] = Wih3[(32 + j) * 32 + 16 * p + c];
        vn[c] = Wih3[(64 + j) * 32 + 16 * p + c];
        ur[c] = Whh3[j * 32 + 16 * p + c];
        uz[c] = Whh3[(32 + j) * 32 + 16 * p + c];
        un[c] = Whh3[(64 + j) * 32 + 16 * p + c];
        wf0[c] = Wfc[j * 32 + 16 * p + c];
        wf1[c] = Wfc[(32 + j) * 32 + 16 * p + c];
        wf2[c] = (j < 31) ? Wfc[(64 + j) * 32 + 16 * p + c] : 0.f;
    }
    const float br = bih3[j] + bhh3[j];
    const float bz = bih3[32 + j] + bhh3[32 + j];
    const float bni = bih3[64 + j], bnh = bhh3[64 + j];
    const float bf0 = bfc[j], bf1 = bfc[32 + j];
    const float bf2 = (j < 31) ? bfc[64 + j] : 0.f;

    const size_t b = (size_t)blockIdx.x * 4 + wid;
    float* orow = out + b * (size_t)(TT * VV);

    if (p == 0) { hb[wid][j] = 0.0f; ist[0][wid][j] = orow[32 + j]; }
    float hj = 0.0f;
    float pnA = orow[1 * VV + 32 + j];
    float pnB = orow[2 * VV + 32 + j];
    wave_fence();

    for (int t = 0; t < TT; t += 2) {
        l3_step(t,     j, p, wid, orow, hb, ist, vr, vz, vn, ur, uz, un,
                wf0, wf1, wf2, br, bz, bni, bnh, bf0, bf1, bf2, hj, pnA);
        l3_step(t + 1, j, p, wid, orow, hb, ist, vr, vz, vn, ur, uz, un,
                wf0, wf1, wf2, br, bz, bni, bnh, bf0, bf1, bf2, hj, pnB);
    }
}

extern "C" void kernel_launch(void* const* d_in, const int* in_sizes, int n_in,
                              void* d_out, int out_size, void* d_ws, size_t ws_size,
                              hipStream_t stream) {
    const float* x    = (const float*)d_in[0];
    const float* Wih1 = (const float*)d_in[1];
    const float* Whh1 = (const float*)d_in[2];
    const float* bih1 = (const float*)d_in[3];
    const float* bhh1 = (const float*)d_in[4];
    const float* Wih2 = (const float*)d_in[5];
    const float* Whh2 = (const float*)d_in[6];
    const float* bih2 = (const float*)d_in[7];
    const float* bhh2 = (const float*)d_in[8];
    const float* Wih3 = (const float*)d_in[9];
    const float* Whh3 = (const float*)d_in[10];
    const float* bih3 = (const float*)d_in[11];
    const float* bhh3 = (const float*)d_in[12];
    const float* Wfc  = (const float*)d_in[13];
    const float* bfc  = (const float*)d_in[14];
    float* out = (float*)d_out;

    hipLaunchKernelGGL(k0_xproj, dim3(8192), dim3(256), 0, stream, x, Wih1, bih1, out);
    hipLaunchKernelGGL(gru_l1r,  dim3(512),  dim3(256), 0, stream, x, Wih1, Whh1, bih1, bhh1, out);
    hipLaunchKernelGGL(gru_l2r,  dim3(512),  dim3(256), 0, stream, Wih2, Whh2, bih2, bhh2, out);
    hipLaunchKernelGGL(gru_l3fc, dim3(512),  dim3(256), 0, stream, Wih3, Whh3, bih3, bhh3, Wfc, bfc, out);
}